// Round 5
// baseline (70.378 us; speedup 1.0000x reference)
//
#include <hip/hip_runtime.h>
#include <cstdint>
#include <cstddef>

// Dims (fixed by the reference)
#define R_   16
#define NH_  8
#define D_   32
#define C_   256
#define B_   16
#define XY_  1024      // 32*32
#define RH_  128       // R_*NH_
#define KD_  4096      // R_*NH_*D_
#define NPOS (B_*XY_)  // 16384 positions

// GEMM tile config: 64x64 tile, per-thread 4m x 4p, K-chunk 64.
// Wave-level LDS broadcast: tn = tid>>4 is 0..3 within a wave -> B reads are
// 4 distinct float4 (64 B); A reads 16 distinct float4 (256 B). 320 B per
// 16 FMA-instr keeps the CU LDS pipe at ~40 B/cyc << 85 -> VALU-issue-bound.
#define MT 64
#define NT 64
#define KC 64

// ---------------------------------------------------------------------------
// Precompute (unchanged; ~HBM/L3-bound on 42 MB of weights):
//   k[d] = Wk[r,h*D+d,:]·rims[r,:] + bk,   v[d] likewise
//   WLt[c][rh] = sum_d k[d]*Wq[rh*D+d, c]   ([k=c][m=rh], ld=RH_ -> GEMM1 A)
//   U[rh][c]   = sum_d v[d]*Wm[c, rh*D+d]   ([k=rh][m=c], ld=C_  -> GEMM2 A)
//   c0[rh]     = sum_d k[d]*bq[rh*D+d]
// ---------------------------------------------------------------------------
__global__ __launch_bounds__(256)
void rims_precompute(const float* __restrict__ rims,
                     const float* __restrict__ Wk,
                     const float* __restrict__ bk,
                     const float* __restrict__ Wv,
                     const float* __restrict__ bv,
                     const float* __restrict__ Wq,
                     const float* __restrict__ bq,
                     const float* __restrict__ Wm,
                     float* __restrict__ WLt,
                     float* __restrict__ Uo,
                     float* __restrict__ c0o)
{
    const int rh  = blockIdx.x;        // 0..127
    const int r   = rh >> 3;
    const int h   = rh & 7;
    const int tid = threadIdx.x;

    __shared__ float ks[D_];
    __shared__ float vs[D_];

    {
        const int idx  = tid >> 2;         // 0..63 : (isv, d)
        const int part = tid & 3;
        const int d    = idx & (D_ - 1);
        const bool isv = (idx >= D_);
        const float* Wrow = (isv ? Wv : Wk) + ((size_t)r * 256 + h * D_ + d) * C_ + part * 64;
        const float* rr   = rims + r * C_ + part * 64;
        float a0 = 0.f, a1 = 0.f, a2 = 0.f, a3 = 0.f;
        #pragma unroll
        for (int j = 0; j < 16; ++j) {
            const float4 w = *reinterpret_cast<const float4*>(Wrow + j * 4);
            const float4 x = *reinterpret_cast<const float4*>(rr + j * 4);
            a0 = fmaf(w.x, x.x, a0); a1 = fmaf(w.y, x.y, a1);
            a2 = fmaf(w.z, x.z, a2); a3 = fmaf(w.w, x.w, a3);
        }
        float acc = (a0 + a1) + (a2 + a3);
        acc += __shfl_xor(acc, 1);
        acc += __shfl_xor(acc, 2);
        if (part == 0) {
            const float val = acc + (isv ? bv : bk)[r * 256 + h * D_ + d];
            if (isv) vs[d] = val; else ks[d] = val;
        }
    }
    __syncthreads();

    {
        const int c = tid;                 // 0..255
        float wl = 0.f, uu = 0.f;
        const float* wqp = Wq + (size_t)rh * D_ * C_ + c;
        const float* wmp = Wm + (size_t)c * KD_ + rh * D_;
        #pragma unroll
        for (int d4 = 0; d4 < D_; d4 += 4) {
            const float4 wm4 = *reinterpret_cast<const float4*>(wmp + d4);
            wl = fmaf(ks[d4 + 0], wqp[(d4 + 0) * C_], wl);
            wl = fmaf(ks[d4 + 1], wqp[(d4 + 1) * C_], wl);
            wl = fmaf(ks[d4 + 2], wqp[(d4 + 2) * C_], wl);
            wl = fmaf(ks[d4 + 3], wqp[(d4 + 3) * C_], wl);
            uu = fmaf(vs[d4 + 0], wm4.x, uu);
            uu = fmaf(vs[d4 + 1], wm4.y, uu);
            uu = fmaf(vs[d4 + 2], wm4.z, uu);
            uu = fmaf(vs[d4 + 3], wm4.w, uu);
        }
        WLt[c * RH_ + rh] = wl;
        Uo[rh * C_ + c]   = uu;
    }

    if (tid < D_) {
        float s = ks[tid] * bq[rh * D_ + tid];
        s += __shfl_xor(s, 1);  s += __shfl_xor(s, 2);  s += __shfl_xor(s, 4);
        s += __shfl_xor(s, 8);  s += __shfl_xor(s, 16);
        if (tid == 0) c0o[rh] = s;
    }
}

// ---------------------------------------------------------------------------
// Tiled GEMM: Cdst[m][p] = sum_k A[k][m0+m] * B[k][p0+p] + bias[m]
//   MODE 0 (GEMM1): A=WLt (ld RH_), B = z ([b][c][xy]), C = L[m*NPOS+p], bias=c0
//   MODE 1 (GEMM2): A=Uo  (ld C_),  B = attn[rh][p],    C = out[b][m][xy], bias=bm
// Block: 256 thr, tile 64x64, per-thread 4x4, KC=64 LDS chunks (32 KB),
// reg-prefetch of chunk t+1 overlapped with compute of chunk t.
// ---------------------------------------------------------------------------
template<int MODE, int K>
__global__ __launch_bounds__(256, 2)
void gemm_kn(const float* __restrict__ A,
             const float* __restrict__ Bsrc,
             const float* __restrict__ bias,
             float* __restrict__ Cdst)
{
    __shared__ float As[KC * MT];  // 16 KB [k][m]
    __shared__ float Bs[KC * NT];  // 16 KB [k][p]

    const int tid = threadIdx.x;
    const int p0  = blockIdx.x * NT;
    const int m0  = blockIdx.y * MT;
    const int ldA = (MODE == 0 ? RH_ : C_);

    const float* Bbase = (MODE == 0)
        ? Bsrc + ((size_t)(p0 >> 10) * C_) * XY_ + (p0 & (XY_ - 1))
        : Bsrc + p0;
    const size_t ldB = (MODE == 0 ? (size_t)XY_ : (size_t)NPOS);

    // staging map: thread covers rows (tid>>4)+{0,16,32,48}, col (tid&15)*4
    const int srow = tid >> 4;             // 0..15
    const int scol = (tid & 15) << 2;      // 0,4,..60

    const float* Ag = A + m0 + scol;
    const float* Bg = Bbase + scol;
    float4 rA[4], rB[4];

    #pragma unroll
    for (int i = 0; i < 4; ++i) {
        rA[i] = *reinterpret_cast<const float4*>(Ag + (size_t)(srow + 16 * i) * ldA);
        rB[i] = *reinterpret_cast<const float4*>(Bg + (size_t)(srow + 16 * i) * ldB);
    }

    const int tm = tid & 15;               // m = m0 + 4*tm + {0..3}
    const int tn = tid >> 4;               // p = p0 + 4*tn + {0..3}; 0..3 per wave
    float acc[4][4];
    #pragma unroll
    for (int i = 0; i < 4; ++i)
        #pragma unroll
        for (int j = 0; j < 4; ++j) acc[i][j] = 0.f;

    constexpr int NTCH = K / KC;
    #pragma unroll
    for (int t = 0; t < NTCH; ++t) {
        #pragma unroll
        for (int i = 0; i < 4; ++i) {
            *reinterpret_cast<float4*>(&As[(srow + 16 * i) * MT + scol]) = rA[i];
            *reinterpret_cast<float4*>(&Bs[(srow + 16 * i) * NT + scol]) = rB[i];
        }
        __syncthreads();

        if (t + 1 < NTCH) {
            const int kc = (t + 1) * KC;
            #pragma unroll
            for (int i = 0; i < 4; ++i) {
                rA[i] = *reinterpret_cast<const float4*>(Ag + (size_t)(kc + srow + 16 * i) * ldA);
                rB[i] = *reinterpret_cast<const float4*>(Bg + (size_t)(kc + srow + 16 * i) * ldB);
            }
        }

        #pragma unroll 4
        for (int k = 0; k < KC; ++k) {
            const float4 a4 = *reinterpret_cast<const float4*>(&As[k * MT + tm * 4]);
            const float4 b4 = *reinterpret_cast<const float4*>(&Bs[k * NT + tn * 4]);
            const float av[4] = {a4.x, a4.y, a4.z, a4.w};
            const float bv[4] = {b4.x, b4.y, b4.z, b4.w};
            #pragma unroll
            for (int i = 0; i < 4; ++i)
                #pragma unroll
                for (int j = 0; j < 4; ++j)
                    acc[i][j] = fmaf(av[i], bv[j], acc[i][j]);
        }
        __syncthreads();
    }

    // epilogue
    #pragma unroll
    for (int i = 0; i < 4; ++i) {
        const int m = m0 + tm * 4 + i;
        const float bb = bias[m];
        float4 st;
        st.x = acc[i][0] + bb; st.y = acc[i][1] + bb;
        st.z = acc[i][2] + bb; st.w = acc[i][3] + bb;
        if (MODE == 0) {
            *reinterpret_cast<float4*>(Cdst + (size_t)m * NPOS + p0 + tn * 4) = st;
        } else {
            float* ob = Cdst + ((size_t)(p0 >> 10) * C_ + m) * XY_ + (p0 & (XY_ - 1)) + tn * 4;
            *reinterpret_cast<float4*>(ob) = st;
        }
    }
}

// ---------------------------------------------------------------------------
// Softmax over r (16 values, row stride NH_*NPOS) per (h, p). In-place on L.
// ---------------------------------------------------------------------------
__global__ __launch_bounds__(256)
void softmax_r(float* __restrict__ L)
{
    const int p = blockIdx.x * 256 + threadIdx.x;  // 0..16383
    const int h = blockIdx.y;                      // 0..7
    float* base = L + (size_t)h * NPOS + p;
    float vals[R_];
    float m = -1e30f;
    #pragma unroll
    for (int r = 0; r < R_; ++r) {
        vals[r] = base[(size_t)r * NH_ * NPOS];
        m = fmaxf(m, vals[r]);
    }
    float s = 0.f;
    #pragma unroll
    for (int r = 0; r < R_; ++r) { vals[r] = __expf(vals[r] - m); s += vals[r]; }
    const float inv = 1.f / s;
    #pragma unroll
    for (int r = 0; r < R_; ++r) base[(size_t)r * NH_ * NPOS] = vals[r] * inv;
}

// ---------------------------------------------------------------------------
// Fallback fused kernel (R2 version) for the case ws_size < ~8.7 MB.
// ---------------------------------------------------------------------------
__global__ __launch_bounds__(512, 2)
void rims_main_fused(const float* __restrict__ z,
                     const float* __restrict__ WLt,
                     const float* __restrict__ Uo,
                     const float* __restrict__ c0v,
                     const float* __restrict__ bm,
                     float* __restrict__ out)
{
    __shared__ float Zs[C_ * 64];
    __shared__ float Ls[RH_ * 64];

    const int tid  = threadIdx.x;
    const int lane = tid & 63;
    const int w    = __builtin_amdgcn_readfirstlane(tid >> 6);
    const int blk  = blockIdx.x;
    const int b    = blk >> 4;
    const int xy0  = (blk & 15) * 64;
    const float* zb = z + ((size_t)b * C_) * XY_ + xy0;

    {
        const int p4 = (tid & 15) << 2;
        const int c0 = tid >> 4;
        #pragma unroll
        for (int i = 0; i < 8; ++i) {
            const int c = c0 + (i << 5);
            *reinterpret_cast<float4*>(&Zs[c * 64 + p4]) =
                *reinterpret_cast<const float4*>(zb + (size_t)c * XY_ + p4);
        }
    }
    __syncthreads();

    {
        const int rh0 = w << 4;
        float acc[16];
        #pragma unroll
        for (int j = 0; j < 16; ++j) acc[j] = 0.f;
        const float* wp = WLt + rh0;
        #pragma unroll 4
        for (int c = 0; c < C_; ++c) {
            const float zv = Zs[c * 64 + lane];
            #pragma unroll
            for (int j = 0; j < 16; ++j)
                acc[j] = fmaf(wp[c * RH_ + j], zv, acc[j]);
        }
        #pragma unroll
        for (int j = 0; j < 16; ++j)
            Ls[(rh0 + j) * 64 + lane] = acc[j] + c0v[rh0 + j];
    }
    __syncthreads();

    {
        float vals[R_];
        float m = -1e30f;
        #pragma unroll
        for (int r = 0; r < R_; ++r) {
            vals[r] = Ls[(r * NH_ + w) * 64 + lane];
            m = fmaxf(m, vals[r]);
        }
        float s = 0.f;
        #pragma unroll
        for (int r = 0; r < R_; ++r) { vals[r] = __expf(vals[r] - m); s += vals[r]; }
        const float inv = 1.f / s;
        #pragma unroll
        for (int r = 0; r < R_; ++r) Ls[(r * NH_ + w) * 64 + lane] = vals[r] * inv;
    }
    __syncthreads();

    {
        const int c0 = w << 5;
        float acc[32];
        #pragma unroll
        for (int j = 0; j < 32; ++j) acc[j] = 0.f;
        const float* up = Uo + c0;
        #pragma unroll 2
        for (int rh = 0; rh < RH_; ++rh) {
            const float av = Ls[rh * 64 + lane];
            #pragma unroll
            for (int j = 0; j < 32; ++j)
                acc[j] = fmaf(up[rh * C_ + j], av, acc[j]);
        }
        float* ob = out + ((size_t)b * C_ + c0) * XY_ + xy0;
        #pragma unroll
        for (int j = 0; j < 32; ++j)
            ob[(size_t)j * XY_ + lane] = acc[j] + bm[c0 + j];
    }
}

// ---------------------------------------------------------------------------
extern "C" void kernel_launch(void* const* d_in, const int* in_sizes, int n_in,
                              void* d_out, int out_size, void* d_ws, size_t ws_size,
                              hipStream_t stream)
{
    const float* z    = (const float*)d_in[0];
    const float* rims = (const float*)d_in[1];
    const float* Wk   = (const float*)d_in[2];
    const float* bk   = (const float*)d_in[3];
    const float* Wv   = (const float*)d_in[4];
    const float* bv   = (const float*)d_in[5];
    const float* Wq   = (const float*)d_in[6];
    const float* bq   = (const float*)d_in[7];
    const float* Wm   = (const float*)d_in[8];
    const float* bm   = (const float*)d_in[9];
    float* out = (float*)d_out;

    // ws layout: WLt (C_*RH_) | Uo (RH_*C_) | c0 (RH_) | pad | L (RH_*NPOS)
    float* WLt = (float*)d_ws;
    float* Uo  = WLt + C_ * RH_;
    float* c0o = Uo + RH_ * C_;
    float* L   = c0o + 256;
    const size_t need = ((size_t)(C_ * RH_ + RH_ * C_ + 256) + (size_t)RH_ * NPOS) * 4;

    rims_precompute<<<RH_, 256, 0, stream>>>(rims, Wk, bk, Wv, bv, Wq, bq, Wm,
                                             WLt, Uo, c0o);

    if (ws_size >= need) {
        dim3 g1(NPOS / NT, RH_ / MT);             // (256, 2)
        gemm_kn<0, C_><<<g1, 256, 0, stream>>>(WLt, z, c0o, L);
        dim3 gs(NPOS / 256, NH_);                 // (64, 8)
        softmax_r<<<gs, 256, 0, stream>>>(L);
        dim3 g2(NPOS / NT, C_ / MT);              // (256, 4)
        gemm_kn<1, RH_><<<g2, 256, 0, stream>>>(Uo, L, bm, out);
    } else {
        rims_main_fused<<<(B_ * XY_) / 64, 512, 0, stream>>>(z, WLt, Uo, c0o, bm, out);
    }
}

// Round 6
// 52.389 us; speedup vs baseline: 1.3434x; 1.3434x over previous
//
#include <hip/hip_runtime.h>
#include <cstdint>
#include <cstddef>

// Dims (fixed by the reference)
#define R_   16
#define NH_  8
#define D_   32
#define C_   256
#define B_   16
#define XY_  1024      // 32*32
#define RH_  128       // R_*NH_
#define KD_  4096      // R_*NH_*D_
#define NT   64        // positions per block (lane = position)

// ---------------------------------------------------------------------------
// Precompute, 2x parallel (256 blocks): bid = rh*2 + half.
//   half 0: k[d] = Wk[r,h*D+d,:]·rims[r,:]+bk  ->  WLt[c][rh], c0[rh]
//   half 1: v[d] = Wv[...]·rims+bv             ->  Uo[rh][c]
// Each block: 32 dots (8 lanes each), then a 256-wide fold.
// ---------------------------------------------------------------------------
__global__ __launch_bounds__(256)
void rims_precompute(const float* __restrict__ rims,
                     const float* __restrict__ Wk,
                     const float* __restrict__ bk,
                     const float* __restrict__ Wv,
                     const float* __restrict__ bv,
                     const float* __restrict__ Wq,
                     const float* __restrict__ bq,
                     const float* __restrict__ Wm,
                     float* __restrict__ WLt,
                     float* __restrict__ Uo,
                     float* __restrict__ c0o)
{
    const int bid  = blockIdx.x;       // 0..255
    const int rh   = bid >> 1;         // 0..127
    const int half = bid & 1;          // 0: k/WLt, 1: v/Uo
    const int r    = rh >> 3;
    const int h    = rh & 7;
    const int tid  = threadIdx.x;

    __shared__ float kv[D_];

    // ---- 32 dot products over C=256, 8 lanes per dot (32 elems each) ----
    {
        const int d    = tid >> 3;     // 0..31
        const int part = tid & 7;      // 0..7
        const float* Wsrc = (half ? Wv : Wk)
                          + ((size_t)r * 256 + h * D_ + d) * C_ + part * 32;
        const float* rr   = rims + r * C_ + part * 32;
        float a0 = 0.f, a1 = 0.f, a2 = 0.f, a3 = 0.f;
        #pragma unroll
        for (int j = 0; j < 8; ++j) {
            const float4 wv4 = *reinterpret_cast<const float4*>(Wsrc + j * 4);
            const float4 xv4 = *reinterpret_cast<const float4*>(rr + j * 4);
            a0 = fmaf(wv4.x, xv4.x, a0); a1 = fmaf(wv4.y, xv4.y, a1);
            a2 = fmaf(wv4.z, xv4.z, a2); a3 = fmaf(wv4.w, xv4.w, a3);
        }
        float acc = (a0 + a1) + (a2 + a3);
        acc += __shfl_xor(acc, 1);
        acc += __shfl_xor(acc, 2);
        acc += __shfl_xor(acc, 4);
        if (part == 0)
            kv[d] = acc + (half ? bv : bk)[r * 256 + h * D_ + d];
    }
    __syncthreads();

    const int c = tid;                 // 0..255
    if (half == 0) {
        float wl = 0.f;
        const float* wqp = Wq + (size_t)rh * D_ * C_ + c;
        #pragma unroll
        for (int d = 0; d < D_; ++d)
            wl = fmaf(kv[d], wqp[(size_t)d * C_], wl);
        WLt[c * RH_ + rh] = wl;        // [c][rh] -> contiguous 8-float rows/wave

        if (tid < D_) {
            float s = kv[tid] * bq[rh * D_ + tid];
            s += __shfl_xor(s, 1);  s += __shfl_xor(s, 2);  s += __shfl_xor(s, 4);
            s += __shfl_xor(s, 8);  s += __shfl_xor(s, 16);
            if (tid == 0) c0o[rh] = s;
        }
    } else {
        float uu = 0.f;
        const float* wmp = Wm + (size_t)c * KD_ + rh * D_;
        #pragma unroll
        for (int d4 = 0; d4 < D_; d4 += 4) {
            const float4 m4 = *reinterpret_cast<const float4*>(wmp + d4);
            uu = fmaf(kv[d4 + 0], m4.x, uu);
            uu = fmaf(kv[d4 + 1], m4.y, uu);
            uu = fmaf(kv[d4 + 2], m4.z, uu);
            uu = fmaf(kv[d4 + 3], m4.w, uu);
        }
        Uo[rh * C_ + c] = uu;          // [rh][c] -> contiguous 16-float rows/wave
    }
}

// ---------------------------------------------------------------------------
// Fused main: 256 blocks (1/CU, zero tail) x 1024 threads (16 waves = 4/SIMD).
// lane = position (64 coalesced positions per block).
//   prologue: issue ALL z global loads (4 float4/thread, named regs)
//   ds_write chunk0 (c 0..127) -> GEMM1 part 1 while chunk1 is in flight
//   ds_write chunk1 -> GEMM1 part 2
//   GEMM1: wave w owns 8 rh rows; weights via uniform s_load (32 B/step)
//   softmax over r per (h,p): waves 0..7
//   GEMM2: wave w owns 16 c rows; U via uniform s_load (64 B/step)
// LDS 96 KB; all vector LDS traffic is lane-stride-1 (2-way alias = free).
// ---------------------------------------------------------------------------
__global__ __launch_bounds__(1024, 4)
void rims_main(const float* __restrict__ z,
               const float* __restrict__ WLt,
               const float* __restrict__ Uo,
               const float* __restrict__ c0v,
               const float* __restrict__ bm,
               float* __restrict__ out)
{
    __shared__ float Zs[C_ * NT];    // 64 KB [c][p]
    __shared__ float Ls[RH_ * NT];   // 32 KB [rh][p]

    const int tid  = threadIdx.x;
    const int lane = tid & 63;
    const int w    = __builtin_amdgcn_readfirstlane(tid >> 6);  // 0..15
    const int b    = blockIdx.x >> 4;
    const int xy0  = (blockIdx.x & 15) * NT;
    const float* zb = z + ((size_t)b * C_) * XY_ + xy0;

    // staging map: row = tid>>4 (0..63), col = (tid&15)*4
    const int srow = tid >> 4;
    const int scol = (tid & 15) << 2;

    // issue all 4 tile-quarters now (named regs -> no scratch risk)
    const float4 z0a = *reinterpret_cast<const float4*>(zb + (size_t)(srow      ) * XY_ + scol);
    const float4 z0b = *reinterpret_cast<const float4*>(zb + (size_t)(srow +  64) * XY_ + scol);
    const float4 z1a = *reinterpret_cast<const float4*>(zb + (size_t)(srow + 128) * XY_ + scol);
    const float4 z1b = *reinterpret_cast<const float4*>(zb + (size_t)(srow + 192) * XY_ + scol);

    *reinterpret_cast<float4*>(&Zs[(srow      ) * NT + scol]) = z0a;
    *reinterpret_cast<float4*>(&Zs[(srow +  64) * NT + scol]) = z0b;
    __syncthreads();

    // ---- GEMM1: wave w -> rh rows [8w, 8w+8), K split 128+128 ----
    const int rh0 = w << 3;
    float acc1[8];
    #pragma unroll
    for (int j = 0; j < 8; ++j) acc1[j] = 0.f;
    const float* wp = WLt + rh0;               // uniform; stride RH_ per c

    #pragma unroll 4
    for (int c = 0; c < 128; ++c) {
        const float zv = Zs[c * NT + lane];
        #pragma unroll
        for (int j = 0; j < 8; ++j)
            acc1[j] = fmaf(wp[c * RH_ + j], zv, acc1[j]);
    }

    // chunk1 arrived long ago; write rows 128..255 (disjoint from part-1 reads)
    *reinterpret_cast<float4*>(&Zs[(srow + 128) * NT + scol]) = z1a;
    *reinterpret_cast<float4*>(&Zs[(srow + 192) * NT + scol]) = z1b;
    __syncthreads();

    #pragma unroll 4
    for (int c = 128; c < 256; ++c) {
        const float zv = Zs[c * NT + lane];
        #pragma unroll
        for (int j = 0; j < 8; ++j)
            acc1[j] = fmaf(wp[c * RH_ + j], zv, acc1[j]);
    }

    #pragma unroll
    for (int j = 0; j < 8; ++j)
        Ls[(rh0 + j) * NT + lane] = acc1[j] + c0v[rh0 + j];
    __syncthreads();

    // ---- softmax over r (16 rims) per (h, p): waves 0..7 ----
    if (tid < 512) {
        const int h = tid >> 6;                // 0..7
        float vals[R_];
        float m = -1e30f;
        #pragma unroll
        for (int r = 0; r < R_; ++r) {
            vals[r] = Ls[(r * NH_ + h) * NT + lane];
            m = fmaxf(m, vals[r]);
        }
        float s = 0.f;
        #pragma unroll
        for (int r = 0; r < R_; ++r) { vals[r] = __expf(vals[r] - m); s += vals[r]; }
        const float inv = 1.f / s;
        #pragma unroll
        for (int r = 0; r < R_; ++r) Ls[(r * NH_ + h) * NT + lane] = vals[r] * inv;
    }
    __syncthreads();

    // ---- GEMM2: wave w -> c rows [16w, 16w+16), K = 128 ----
    const int c0 = w << 4;
    float acc2[16];
    #pragma unroll
    for (int j = 0; j < 16; ++j) acc2[j] = 0.f;
    const float* up = Uo + c0;                 // uniform; stride C_ per rh

    #pragma unroll 2
    for (int rh = 0; rh < RH_; ++rh) {
        const float av = Ls[rh * NT + lane];
        #pragma unroll
        for (int j = 0; j < 16; ++j)
            acc2[j] = fmaf(up[rh * C_ + j], av, acc2[j]);
    }

    float* ob = out + ((size_t)b * C_ + c0) * XY_ + xy0;
    #pragma unroll
    for (int j = 0; j < 16; ++j)
        ob[(size_t)j * XY_ + lane] = acc2[j] + bm[c0 + j];
}

// ---------------------------------------------------------------------------
extern "C" void kernel_launch(void* const* d_in, const int* in_sizes, int n_in,
                              void* d_out, int out_size, void* d_ws, size_t ws_size,
                              hipStream_t stream)
{
    const float* z    = (const float*)d_in[0];
    const float* rims = (const float*)d_in[1];
    const float* Wk   = (const float*)d_in[2];
    const float* bk   = (const float*)d_in[3];
    const float* Wv   = (const float*)d_in[4];
    const float* bv   = (const float*)d_in[5];
    const float* Wq   = (const float*)d_in[6];
    const float* bq   = (const float*)d_in[7];
    const float* Wm   = (const float*)d_in[8];
    const float* bm   = (const float*)d_in[9];
    float* out = (float*)d_out;

    // ws layout: WLt (C_*RH_) | Uo (RH_*C_) | c0 (RH_)  -> ~257 KB
    float* WLt = (float*)d_ws;
    float* Uo  = WLt + C_ * RH_;
    float* c0o = Uo + RH_ * C_;

    rims_precompute<<<2 * RH_, 256, 0, stream>>>(rims, Wk, bk, Wv, bv, Wq, bq, Wm,
                                                 WLt, Uo, c0o);
    rims_main<<<(B_ * XY_) / NT, 1024, 0, stream>>>(z, WLt, Uo, c0o, bm, out);
}